// Round 1
// baseline (5376.074 us; speedup 1.0000x reference)
//
#include <hip/hip_runtime.h>
#include <cmath>

#define BB 64
#define TT 2048
#define FF 64
#define HH 160
#define G3 480

typedef unsigned int u32;
typedef _Float16 __attribute__((ext_vector_type(2))) half2v;

__device__ __forceinline__ unsigned short f2h(float x) {
    _Float16 h = (_Float16)x;
    return __builtin_bit_cast(unsigned short, h);
}
__device__ __forceinline__ u32 packh2(float a, float b) {
    return (u32)f2h(a) | ((u32)f2h(b) << 16);
}
__device__ __forceinline__ float fdot2(u32 w, u32 v, float acc) {
    return __builtin_amdgcn_fdot2(__builtin_bit_cast(half2v, w),
                                  __builtin_bit_cast(half2v, v), acc, false);
}
__device__ __forceinline__ float fsigmoid(float x) { return 1.f / (1.f + __expf(-x)); }
__device__ __forceinline__ float ftanhf(float x) {
    float xc = fminf(fmaxf(x, -15.f), 15.f);
    float e = __expf(2.f * xc);
    return 1.f - 2.f / (e + 1.f);
}
__device__ __forceinline__ float gelu_exact(float x) {
    return 0.5f * x * (1.f + erff(x * 0.70710678118654752f));
}

// ---------------------------------------------------------------------------
// K1: dilated conv (k=3, dil=2, pad=2) + BN(inference) + exact GELU
// out: z packed as f16 pairs [B, T, 32] u32
// grid: (16 t-slabs of 128, B), block: 256 (lane f = output channel)
// ---------------------------------------------------------------------------
__global__ __launch_bounds__(256) void conv_bn_gelu_kernel(
    const float* __restrict__ x, const float* __restrict__ mix_w,
    const float* __restrict__ bn_g, const float* __restrict__ bn_b,
    const float* __restrict__ bn_m, const float* __restrict__ bn_v,
    u32* __restrict__ z_out)
{
    __shared__ float ws_w[3][64][64];   // [k][fi][fo] — lanes read consecutive fo
    __shared__ float ws_x[132][64];     // t0-2 .. t0+129
    const int b  = blockIdx.y;
    const int t0 = blockIdx.x * 128;
    const int tid = threadIdx.x;
    const int f  = tid & 63;   // output channel (lane)
    const int rg = tid >> 6;   // row group 0..3

    // load weights transposed: mix_w layout [fo][fi][k]
    for (int idx = tid; idx < 64 * 64 * 3; idx += 256) {
        int fo = idx / 192;
        int rem = idx - fo * 192;
        int fi = rem / 3;
        int k  = rem - fi * 3;
        ws_w[k][fi][fo] = mix_w[idx];
    }
    // load x tile (zero padded at sequence edges)
    for (int row = rg; row < 132; row += 4) {
        int t = t0 - 2 + row;
        ws_x[row][f] = (t >= 0 && t < TT) ? x[((size_t)b * TT + t) * FF + f] : 0.f;
    }
    __syncthreads();

    const float scale = bn_g[f] * rsqrtf(bn_v[f] + 1e-5f);
    const float shift = bn_b[f] - bn_m[f] * scale;

    for (int ti = rg; ti < 128; ti += 4) {
        float acc = 0.f;
        #pragma unroll
        for (int k = 0; k < 3; ++k) {
            const float* xr = &ws_x[ti + 2 * k][0];
            #pragma unroll
            for (int fi = 0; fi < 64; ++fi)
                acc = fmaf(xr[fi], ws_w[k][fi][f], acc);
        }
        float y = fmaf(acc, scale, shift);
        float z = gelu_exact(y);
        float zp = __shfl_xor(z, 1);
        if ((f & 1) == 0)
            z_out[((size_t)b * TT + (t0 + ti)) * 32 + (f >> 1)] = packh2(z, zp);
    }
}

// ---------------------------------------------------------------------------
// K2: GRU1 scan. One block per batch element, 512 threads.
// Thread r<480 owns gate row r: W_hh1 row fp32 (160 VGPR) + W_ih1 row f16x2 (32 VGPR).
// h1 states written to global as f16 for pass 2.
// ---------------------------------------------------------------------------
__global__ __launch_bounds__(512, 2) void gru1_kernel(
    const u32* __restrict__ z_f16, const float* __restrict__ w_ih1,
    const float* __restrict__ w_hh1, const float* __restrict__ b_ih1,
    const float* __restrict__ b_hh1, unsigned short* __restrict__ h1_out)
{
    const int b = blockIdx.x;
    const int tid = threadIdx.x;
    __shared__ float4 ld_h4[40];   // h1 fp32
    __shared__ uint4  ld_z4[8];    // z_t f16 pairs
    __shared__ float  ld_g[960];   // partials: [r]=ih, [480+r]=hh
    float* ld_h = (float*)ld_h4;
    u32*   ld_z = (u32*)ld_z4;

    float4 whh[40];
    u32    wih[32];
    float  bih = 0.f, bhh = 0.f;
    if (tid < G3) {
        const float4* wr = (const float4*)(w_hh1 + (size_t)tid * HH);
        #pragma unroll
        for (int c = 0; c < 40; ++c) whh[c] = wr[c];
        const float2* wi = (const float2*)(w_ih1 + (size_t)tid * FF);
        #pragma unroll
        for (int j = 0; j < 32; ++j) { float2 v = wi[j]; wih[j] = packh2(v.x, v.y); }
        bih = b_ih1[tid];
        bhh = b_hh1[tid];
    }
    if (tid < HH) ld_h[tid] = 0.f;
    if (tid < 32) ld_z[tid] = z_f16[((size_t)b * TT) * 32 + tid];
    __syncthreads();

    for (int t = 0; t < TT; ++t) {
        u32 znext = 0;
        if (tid < 32 && t + 1 < TT)
            znext = z_f16[((size_t)b * TT + t + 1) * 32 + tid];
        if (tid < G3) {
            float aih = bih;
            #pragma unroll
            for (int j = 0; j < 8; ++j) {
                uint4 zz = ld_z4[j];
                aih = fdot2(wih[4 * j + 0], zz.x, aih);
                aih = fdot2(wih[4 * j + 1], zz.y, aih);
                aih = fdot2(wih[4 * j + 2], zz.z, aih);
                aih = fdot2(wih[4 * j + 3], zz.w, aih);
            }
            float ahh = bhh;
            #pragma unroll
            for (int c = 0; c < 40; ++c) {
                float4 hh = ld_h4[c];
                ahh = fmaf(whh[c].x, hh.x, ahh);
                ahh = fmaf(whh[c].y, hh.y, ahh);
                ahh = fmaf(whh[c].z, hh.z, ahh);
                ahh = fmaf(whh[c].w, hh.w, ahh);
            }
            ld_g[tid] = aih;
            ld_g[480 + tid] = ahh;
        }
        __syncthreads();
        if (tid < HH) {
            float r = fsigmoid(ld_g[tid] + ld_g[480 + tid]);
            float u = fsigmoid(ld_g[160 + tid] + ld_g[640 + tid]);
            float n = ftanhf(ld_g[320 + tid] + r * ld_g[800 + tid]);
            float hnew = (1.f - u) * n + u * ld_h[tid];
            ld_h[tid] = hnew;
            h1_out[((size_t)b * TT + t) * HH + tid] = f2h(hnew);
        }
        if (tid < 32) ld_z[tid] = znext;
        __syncthreads();
    }
}

// ---------------------------------------------------------------------------
// K3: GRU2 scan (all-dot2: both weight matrices f16-packed, 160 VGPR) + MLP head.
// h2 state kept fp32 in each gate thread's register; f16 copy in LDS for dots.
// ---------------------------------------------------------------------------
__global__ __launch_bounds__(512, 2) void gru2_head_kernel(
    const u32* __restrict__ h1_f16, const float* __restrict__ w_ih2,
    const float* __restrict__ w_hh2, const float* __restrict__ b_ih2,
    const float* __restrict__ b_hh2, const float* __restrict__ hw1,
    const float* __restrict__ hb1, const float* __restrict__ hw2,
    const float* __restrict__ hb2, float* __restrict__ out)
{
    const int b = blockIdx.x;
    const int tid = threadIdx.x;
    __shared__ uint4 ld_x4[20];    // h1_t f16 pairs
    __shared__ uint4 ld_hh4[20];   // h2 f16 pairs
    __shared__ float ld_g[960];
    __shared__ float ld_hf[HH];
    u32* ld_x = (u32*)ld_x4;
    _Float16* ld_hhh = (_Float16*)ld_hh4;

    u32 wih[80], whh[80];
    float bih = 0.f, bhh = 0.f;
    if (tid < G3) {
        const float2* a = (const float2*)(w_ih2 + (size_t)tid * HH);
        const float2* c = (const float2*)(w_hh2 + (size_t)tid * HH);
        #pragma unroll
        for (int j = 0; j < 80; ++j) { float2 v = a[j]; wih[j] = packh2(v.x, v.y); }
        #pragma unroll
        for (int j = 0; j < 80; ++j) { float2 v = c[j]; whh[j] = packh2(v.x, v.y); }
        bih = b_ih2[tid];
        bhh = b_hh2[tid];
    }
    float h2 = 0.f;  // valid for tid<160
    if (tid < 80) {
        ld_x[tid] = h1_f16[((size_t)b * TT) * 80 + tid];
        ((u32*)ld_hh4)[tid] = 0;
    }
    __syncthreads();

    for (int t = 0; t < TT; ++t) {
        u32 xnext = 0;
        if (tid < 80 && t + 1 < TT)
            xnext = h1_f16[((size_t)b * TT + t + 1) * 80 + tid];
        if (tid < G3) {
            float aih = bih, ahh = bhh;
            #pragma unroll
            for (int j = 0; j < 20; ++j) {
                uint4 xx = ld_x4[j];
                aih = fdot2(wih[4 * j + 0], xx.x, aih);
                aih = fdot2(wih[4 * j + 1], xx.y, aih);
                aih = fdot2(wih[4 * j + 2], xx.z, aih);
                aih = fdot2(wih[4 * j + 3], xx.w, aih);
                uint4 hh = ld_hh4[j];
                ahh = fdot2(whh[4 * j + 0], hh.x, ahh);
                ahh = fdot2(whh[4 * j + 1], hh.y, ahh);
                ahh = fdot2(whh[4 * j + 2], hh.z, ahh);
                ahh = fdot2(whh[4 * j + 3], hh.w, ahh);
            }
            ld_g[tid] = aih;
            ld_g[480 + tid] = ahh;
        }
        __syncthreads();
        if (tid < HH) {
            float r = fsigmoid(ld_g[tid] + ld_g[480 + tid]);
            float u = fsigmoid(ld_g[160 + tid] + ld_g[640 + tid]);
            float n = ftanhf(ld_g[320 + tid] + r * ld_g[800 + tid]);
            h2 = (1.f - u) * n + u * h2;
            ld_hhh[tid] = (_Float16)h2;
        }
        if (tid < 80) ld_x[tid] = xnext;
        __syncthreads();
    }

    // head: q = gelu(h2 @ hw1^T + hb1); out = q @ hw2^T + hb2
    if (tid < HH) ld_hf[tid] = h2;
    __syncthreads();
    if (tid < 80) {
        float q = hb1[tid];
        const float* wr = hw1 + (size_t)tid * HH;
        #pragma unroll 8
        for (int i = 0; i < HH; ++i) q = fmaf(wr[i], ld_hf[i], q);
        q = gelu_exact(q);
        ld_g[tid] = q;
    }
    __syncthreads();
    if (tid < 2) {
        float o = hb2[tid];
        const float* wr = hw2 + tid * 80;
        #pragma unroll 8
        for (int j = 0; j < 80; ++j) o = fmaf(wr[j], ld_g[j], o);
        out[b * 2 + tid] = o;
    }
}

// ---------------------------------------------------------------------------
extern "C" void kernel_launch(void* const* d_in, const int* in_sizes, int n_in,
                              void* d_out, int out_size, void* d_ws, size_t ws_size,
                              hipStream_t stream)
{
    const float* x     = (const float*)d_in[0];
    const float* mix_w = (const float*)d_in[1];
    const float* bn_g  = (const float*)d_in[2];
    const float* bn_b  = (const float*)d_in[3];
    const float* bn_m  = (const float*)d_in[4];
    const float* bn_v  = (const float*)d_in[5];
    const float* w_ih1 = (const float*)d_in[6];
    const float* w_hh1 = (const float*)d_in[7];
    const float* b_ih1 = (const float*)d_in[8];
    const float* b_hh1 = (const float*)d_in[9];
    const float* w_ih2 = (const float*)d_in[10];
    const float* w_hh2 = (const float*)d_in[11];
    const float* b_ih2 = (const float*)d_in[12];
    const float* b_hh2 = (const float*)d_in[13];
    const float* hw1   = (const float*)d_in[14];
    const float* hb1   = (const float*)d_in[15];
    const float* hw2   = (const float*)d_in[16];
    const float* hb2   = (const float*)d_in[17];
    float* out = (float*)d_out;

    // workspace layout: z f16 pairs [B,T,32]u32 (16.78 MB) | h1 f16 [B,T,160]u16 (41.94 MB)
    u32* z_ws = (u32*)d_ws;
    unsigned short* h1_ws =
        (unsigned short*)((char*)d_ws + (size_t)BB * TT * 32 * sizeof(u32));

    conv_bn_gelu_kernel<<<dim3(16, BB), 256, 0, stream>>>(
        x, mix_w, bn_g, bn_b, bn_m, bn_v, z_ws);
    gru1_kernel<<<BB, 512, 0, stream>>>(
        z_ws, w_ih1, w_hh1, b_ih1, b_hh1, h1_ws);
    gru2_head_kernel<<<BB, 512, 0, stream>>>(
        (const u32*)h1_ws, w_ih2, w_hh2, b_ih2, b_hh2, hw1, hb1, hw2, hb2, out);
}

// Round 3
// 5316.257 us; speedup vs baseline: 1.0113x; 1.0113x over previous
//
#include <hip/hip_runtime.h>
#include <cmath>

#define BB 64
#define TT 2048
#define FF 64
#define HH 160
#define G3 480
#define TC 256            // time-chunk length
#define NC (TT / TC)      // 8 chunks

typedef unsigned int u32;
typedef _Float16 half2v __attribute__((ext_vector_type(2)));

__device__ __forceinline__ unsigned short f2h(float x) {
    _Float16 h = (_Float16)x;
    return __builtin_bit_cast(unsigned short, h);
}
__device__ __forceinline__ u32 packh2(float a, float b) {
    return (u32)f2h(a) | ((u32)f2h(b) << 16);
}
__device__ __forceinline__ float fdot2(u32 w, u32 v, float acc) {
    return __builtin_amdgcn_fdot2(__builtin_bit_cast(half2v, w),
                                  __builtin_bit_cast(half2v, v), acc, false);
}
__device__ __forceinline__ u32 rdlane(u32 v, int l) {
    return (u32)__builtin_amdgcn_readlane((int)v, l);
}
__device__ __forceinline__ float fsigmoid(float x) { return 1.f / (1.f + __expf(-x)); }
__device__ __forceinline__ float ftanhf(float x) {
    float xc = fminf(fmaxf(x, -15.f), 15.f);
    float e = __expf(2.f * xc);
    return 1.f - 2.f / (e + 1.f);
}
__device__ __forceinline__ float gelu_exact(float x) {
    return 0.5f * x * (1.f + erff(x * 0.70710678118654752f));
}

// ---------------------------------------------------------------------------
// K1: dilated conv (k=3, dil=2, pad=2) + BN + exact GELU -> z f16 pairs [B,T,32]u32
// (unchanged from R1 — passed)
// ---------------------------------------------------------------------------
__global__ __launch_bounds__(256) void conv_bn_gelu_kernel(
    const float* __restrict__ x, const float* __restrict__ mix_w,
    const float* __restrict__ bn_g, const float* __restrict__ bn_b,
    const float* __restrict__ bn_m, const float* __restrict__ bn_v,
    u32* __restrict__ z_out)
{
    __shared__ float ws_w[3][64][64];
    __shared__ float ws_x[132][64];
    const int b  = blockIdx.y;
    const int t0 = blockIdx.x * 128;
    const int tid = threadIdx.x;
    const int f  = tid & 63;
    const int rg = tid >> 6;

    for (int idx = tid; idx < 64 * 64 * 3; idx += 256) {
        int fo = idx / 192;
        int rem = idx - fo * 192;
        int fi = rem / 3;
        int k  = rem - fi * 3;
        ws_w[k][fi][fo] = mix_w[idx];
    }
    for (int row = rg; row < 132; row += 4) {
        int t = t0 - 2 + row;
        ws_x[row][f] = (t >= 0 && t < TT) ? x[((size_t)b * TT + t) * FF + f] : 0.f;
    }
    __syncthreads();

    const float scale = bn_g[f] * rsqrtf(bn_v[f] + 1e-5f);
    const float shift = bn_b[f] - bn_m[f] * scale;

    for (int ti = rg; ti < 128; ti += 4) {
        float acc = 0.f;
        #pragma unroll
        for (int k = 0; k < 3; ++k) {
            const float* xr = &ws_x[ti + 2 * k][0];
            #pragma unroll
            for (int fi = 0; fi < 64; ++fi)
                acc = fmaf(xr[fi], ws_w[k][fi][f], acc);
        }
        float y = fmaf(acc, scale, shift);
        float z = gelu_exact(y);
        float zp = __shfl_xor(z, 1);
        if ((f & 1) == 0)
            z_out[((size_t)b * TT + (t0 + ti)) * 32 + (f >> 1)] = packh2(z, zp);
    }
}

// ---------------------------------------------------------------------------
// K2: readlane GEMM. xg[m, :] = bias + in[m,:] . W^T   for a 64-row m-tile.
// No LDS. Each lane holds one z-row (K2 uint4 regs); rows broadcast by
// v_readlane; W f16-packed in VGPRs (2 gate rows per thread, 240 workers).
// grid: (TC/64, B); block 256.
// ---------------------------------------------------------------------------
template<int K2>
__global__ __launch_bounds__(256, 1) void xg_gemm_kernel(
    const u32* __restrict__ in, int in_stride_rows, int row0,
    const float* __restrict__ W, const float* __restrict__ bias,
    float* __restrict__ out)
{
    const int tid  = threadIdx.x;
    const int lane = tid & 63;
    const int b    = blockIdx.y;
    const int mt   = blockIdx.x;           // 64-row tile index within chunk
    const size_t in_row  = (size_t)b * in_stride_rows + row0 + mt * 64 + lane;
    const size_t out_row = (size_t)b * TC + mt * 64;

    // every lane loads its z-row into registers (uncoalesced but tiny & L2-hot)
    uint4 zr[K2 / 4];
    const uint4* gz = (const uint4*)(in + in_row * K2);
    #pragma unroll
    for (int k = 0; k < K2 / 4; ++k) zr[k] = gz[k];

    u32 w0[K2], w1[K2];
    float bb0 = 0.f, bb1 = 0.f;
    const int r0 = 2 * tid, r1 = 2 * tid + 1;
    if (tid < 240) {
        const float2* a = (const float2*)(W + (size_t)r0 * (2 * K2));
        const float2* c = (const float2*)(W + (size_t)r1 * (2 * K2));
        #pragma unroll
        for (int j = 0; j < K2; ++j) { float2 v = a[j]; w0[j] = packh2(v.x, v.y); }
        #pragma unroll
        for (int j = 0; j < K2; ++j) { float2 v = c[j]; w1[j] = packh2(v.x, v.y); }
        bb0 = bias[r0];
        bb1 = bias[r1];
    }

    float2* out2 = (float2*)out;
    for (int m = 0; m < 64; ++m) {
        if (tid < 240) {
            float a0 = bb0, a1 = bb1;
            #pragma unroll
            for (int k = 0; k < K2 / 4; ++k) {
                u32 p0 = rdlane(zr[k].x, m);
                u32 p1 = rdlane(zr[k].y, m);
                u32 p2 = rdlane(zr[k].z, m);
                u32 p3 = rdlane(zr[k].w, m);
                a0 = fdot2(w0[4 * k + 0], p0, a0);
                a0 = fdot2(w0[4 * k + 1], p1, a0);
                a0 = fdot2(w0[4 * k + 2], p2, a0);
                a0 = fdot2(w0[4 * k + 3], p3, a0);
                a1 = fdot2(w1[4 * k + 0], p0, a1);
                a1 = fdot2(w1[4 * k + 1], p1, a1);
                a1 = fdot2(w1[4 * k + 2], p2, a1);
                a1 = fdot2(w1[4 * k + 3], p3, a1);
            }
            out2[(out_row + m) * 240 + tid] = (float2){a0, a1};
        }
    }
}

// ---------------------------------------------------------------------------
// K3: GRU scan chunk. 64 blocks (one per chain), 256 threads, 2 gate rows each.
// W_hh f16-packed in 160 VGPRs; h broadcast via 1 ds_read_b128 + v_readlane
// into SGPRs (wave-uniform) — avoids the LDS-return-pipe bottleneck.
// ---------------------------------------------------------------------------
__global__ __launch_bounds__(256, 1) void gru_scan_kernel(
    const float* __restrict__ xg,        // [B, TC, 480] f32 (chunk)
    const float* __restrict__ w_hh,      // [480, 160] f32
    const float* __restrict__ b_hh,      // [480]
    float* __restrict__ h_state,         // [B, 160] f32 carry
    unsigned short* __restrict__ h_out,  // [B, TC, 160] f16, or nullptr
    int first)
{
    const int b = blockIdx.x;
    const int tid = threadIdx.x;
    const int lane = tid & 63;
    __shared__ uint4 ld_h4[20];   // h as f16 (160)
    __shared__ float ld_g[480];
    __shared__ float ld_xn[160];

    u32 w0[80], w1[80];
    float bh0 = 0.f, bh1 = 0.f;
    const int r0 = 2 * tid, r1 = 2 * tid + 1;
    if (tid < 240) {
        const float2* a = (const float2*)(w_hh + (size_t)r0 * HH);
        const float2* c = (const float2*)(w_hh + (size_t)r1 * HH);
        #pragma unroll
        for (int j = 0; j < 80; ++j) { float2 v = a[j]; w0[j] = packh2(v.x, v.y); }
        #pragma unroll
        for (int j = 0; j < 80; ++j) { float2 v = c[j]; w1[j] = packh2(v.x, v.y); }
        bh0 = b_hh[r0];
        bh1 = b_hh[r1];
    }
    float h = 0.f;
    if (tid < HH) {
        h = first ? 0.f : h_state[b * HH + tid];
        ((_Float16*)ld_h4)[tid] = (_Float16)h;
    }
    const float2* xgp = (const float2*)(xg + (size_t)b * TC * G3) + tid;
    float2 xcur = {0.f, 0.f};
    if (tid < 240) xcur = xgp[0];
    __syncthreads();

    for (int t = 0; t < TC; ++t) {
        float2 xnext = {0.f, 0.f};
        if (tid < 240 && t + 1 < TC) xnext = xgp[(size_t)(t + 1) * 240];
        if (tid < 240) {
            const int l = lane < 20 ? lane : 0;
            const uint4 hv = ld_h4[l];
            float a0 = bh0, a1 = bh1;
            #pragma unroll
            for (int j = 0; j < 20; ++j) {
                u32 p0 = rdlane(hv.x, j);
                u32 p1 = rdlane(hv.y, j);
                u32 p2 = rdlane(hv.z, j);
                u32 p3 = rdlane(hv.w, j);
                a0 = fdot2(w0[4 * j + 0], p0, a0);
                a0 = fdot2(w0[4 * j + 1], p1, a0);
                a0 = fdot2(w0[4 * j + 2], p2, a0);
                a0 = fdot2(w0[4 * j + 3], p3, a0);
                a1 = fdot2(w1[4 * j + 0], p0, a1);
                a1 = fdot2(w1[4 * j + 1], p1, a1);
                a1 = fdot2(w1[4 * j + 2], p2, a1);
                a1 = fdot2(w1[4 * j + 3], p3, a1);
            }
            if (r0 < 320) {
                ld_g[r0] = a0 + xcur.x;
                ld_g[r1] = a1 + xcur.y;
            } else {
                ld_g[r0] = a0;
                ld_g[r1] = a1;
                ld_xn[r0 - 320] = xcur.x;
                ld_xn[r1 - 320] = xcur.y;
            }
        }
        __syncthreads();
        if (tid < HH) {
            float r = fsigmoid(ld_g[tid]);
            float u = fsigmoid(ld_g[160 + tid]);
            float n = ftanhf(ld_xn[tid] + r * ld_g[320 + tid]);
            h = (1.f - u) * n + u * h;
            ((_Float16*)ld_h4)[tid] = (_Float16)h;
            if (h_out) h_out[((size_t)b * TC + t) * HH + tid] = f2h(h);
        }
        xcur = xnext;
        __syncthreads();
    }
    if (tid < HH) h_state[b * HH + tid] = h;
}

// ---------------------------------------------------------------------------
// K4: MLP head from h2 final state.
// ---------------------------------------------------------------------------
__global__ __launch_bounds__(256) void head_kernel(
    const float* __restrict__ h_state,
    const float* __restrict__ hw1, const float* __restrict__ hb1,
    const float* __restrict__ hw2, const float* __restrict__ hb2,
    float* __restrict__ out)
{
    const int b = blockIdx.x;
    const int tid = threadIdx.x;
    __shared__ float hf[HH];
    __shared__ float q[80];
    if (tid < HH) hf[tid] = h_state[b * HH + tid];
    __syncthreads();
    if (tid < 80) {
        float a = hb1[tid];
        const float* wr = hw1 + (size_t)tid * HH;
        #pragma unroll 8
        for (int i = 0; i < HH; ++i) a = fmaf(wr[i], hf[i], a);
        q[tid] = gelu_exact(a);
    }
    __syncthreads();
    if (tid < 2) {
        float o = hb2[tid];
        const float* wr = hw2 + tid * 80;
        #pragma unroll 8
        for (int j = 0; j < 80; ++j) o = fmaf(wr[j], q[j], o);
        out[b * 2 + tid] = o;
    }
}

// ---------------------------------------------------------------------------
extern "C" void kernel_launch(void* const* d_in, const int* in_sizes, int n_in,
                              void* d_out, int out_size, void* d_ws, size_t ws_size,
                              hipStream_t stream)
{
    const float* x     = (const float*)d_in[0];
    const float* mix_w = (const float*)d_in[1];
    const float* bn_g  = (const float*)d_in[2];
    const float* bn_b  = (const float*)d_in[3];
    const float* bn_m  = (const float*)d_in[4];
    const float* bn_v  = (const float*)d_in[5];
    const float* w_ih1 = (const float*)d_in[6];
    const float* w_hh1 = (const float*)d_in[7];
    const float* b_ih1 = (const float*)d_in[8];
    const float* b_hh1 = (const float*)d_in[9];
    const float* w_ih2 = (const float*)d_in[10];
    const float* w_hh2 = (const float*)d_in[11];
    const float* b_ih2 = (const float*)d_in[12];
    const float* b_hh2 = (const float*)d_in[13];
    const float* hw1   = (const float*)d_in[14];
    const float* hb1   = (const float*)d_in[15];
    const float* hw2   = (const float*)d_in[16];
    const float* hb2   = (const float*)d_in[17];
    float* out = (float*)d_out;

    // ws (53.6 MB total, proven-safe < 58.7 MB):
    //   z   f16-pairs [B,T,32]u32   16.78 MB
    //   xg  f32 chunk [B,TC,480]    31.46 MB  (shared by layer1/layer2)
    //   h1c f16 chunk [B,TC,160]     5.24 MB
    //   h1s,h2s f32 [B,160]          2 x 40 KB
    char* p = (char*)d_ws;
    u32* z_ws = (u32*)p;                  p += (size_t)BB * TT * 32 * 4;
    float* xg_ws = (float*)p;             p += (size_t)BB * TC * G3 * 4;
    unsigned short* h1c_ws = (unsigned short*)p;  p += (size_t)BB * TC * HH * 2;
    float* h1s = (float*)p;               p += (size_t)BB * HH * 4;
    float* h2s = (float*)p;

    conv_bn_gelu_kernel<<<dim3(16, BB), 256, 0, stream>>>(
        x, mix_w, bn_g, bn_b, bn_m, bn_v, z_ws);

    for (int c = 0; c < NC; ++c) {
        const int first = (c == 0) ? 1 : 0;
        // layer 1: xg1 = z_chunk @ W_ih1^T + b_ih1 ; scan -> h1 chunk (f16)
        xg_gemm_kernel<32><<<dim3(TC / 64, BB), 256, 0, stream>>>(
            z_ws, TT, c * TC, w_ih1, b_ih1, xg_ws);
        gru_scan_kernel<<<BB, 256, 0, stream>>>(
            xg_ws, w_hh1, b_hh1, h1s, h1c_ws, first);
        // layer 2: xg2 = h1_chunk @ W_ih2^T + b_ih2 ; scan (state only)
        xg_gemm_kernel<80><<<dim3(TC / 64, BB), 256, 0, stream>>>(
            (const u32*)h1c_ws, TC, 0, w_ih2, b_ih2, xg_ws);
        gru_scan_kernel<<<BB, 256, 0, stream>>>(
            xg_ws, w_hh2, b_hh2, h2s, nullptr, first);
    }

    head_kernel<<<BB, 256, 0, stream>>>(h2s, hw1, hb1, hw2, hb2, out);
}